// Round 2
// baseline (425.213 us; speedup 1.0000x reference)
//
#include <hip/hip_runtime.h>
#include <hip/hip_bf16.h>
#include <math.h>

#define NN 262144
#define QQ 256
#define CC 160   // 2*P*S combined columns: [0,80)=u (x@beta_u), [80,160)=tz (x@beta_z)
#define PS 80    // P*S
#define BB 4096

// ---------------------------------------------------------------------------
// Kernel 1: segment boundaries via binary search (seg_ids is sorted).
// NOTE: harness delivers integer inputs as int32 (reference int64 is narrowed).
// segstart[b] = lower_bound(seg_ids, b); segstart[BB] = NN.
// ---------------------------------------------------------------------------
__global__ void seg_bounds_k(const int* __restrict__ seg,
                             int* __restrict__ segstart) {
  int b = blockIdx.x * blockDim.x + threadIdx.x;
  if (b > BB) return;
  if (b == BB) { segstart[BB] = NN; return; }
  int lo = 0, hi = NN;
  while (lo < hi) {
    int mid = (lo + hi) >> 1;
    if (seg[mid] < b) lo = mid + 1; else hi = mid;
  }
  segstart[b] = lo;
}

// ---------------------------------------------------------------------------
// Kernel 2: fused f32 GEMM  ut[N][160] = x[N][256] @ [beta_u | beta_z][256][160]
// Tile: 128 rows x 160 cols per block, 256 threads (tx=8 col-groups of 20,
// ty=32 row-groups of 4). K staged in chunks of 32 through LDS.
// x staged TRANSPOSED xt[k][row] (LDA=132 -> 16B-aligned rows, conflict-free
// b128 reads: ty in a wave spans banks {4ty..4ty+3}, disjoint).
// B cols read at 20-float stride: byte offset 80*tx -> 8 disjoint bank quads.
// ---------------------------------------------------------------------------
__global__ __launch_bounds__(256) void gemm_k(
    const float* __restrict__ x, const float* __restrict__ bu,
    const float* __restrict__ bz, float* __restrict__ ut) {
  __shared__ float xt[32][132];
  __shared__ float bt[32][160];
  const int tid = threadIdx.x;
  const int tx = tid & 7;    // 0..7  : 20 cols each
  const int ty = tid >> 3;   // 0..31 : 4 rows each
  const size_t r0 = (size_t)blockIdx.x * 128;

  float acc[4][20];
#pragma unroll
  for (int m = 0; m < 4; ++m)
#pragma unroll
    for (int n = 0; n < 20; ++n) acc[m][n] = 0.f;

  for (int kc = 0; kc < QQ; kc += 32) {
    __syncthreads();  // WAR: previous iter's reads done before overwrite
    // stage x tile (128 rows x 32 k) transposed into xt
#pragma unroll
    for (int i = 0; i < 4; ++i) {
      int idx = tid + 256 * i;
      int row = idx >> 3;
      int j4  = idx & 7;
      float4 v = *reinterpret_cast<const float4*>(
          &x[(r0 + (size_t)row) * QQ + kc + 4 * j4]);
      xt[4 * j4 + 0][row] = v.x;
      xt[4 * j4 + 1][row] = v.y;
      xt[4 * j4 + 2][row] = v.z;
      xt[4 * j4 + 3][row] = v.w;
    }
    // stage combined B tile (32 k x 160 cols)
#pragma unroll
    for (int i = 0; i < 5; ++i) {
      int idx = tid + 256 * i;
      int row = idx / 40;
      int c4  = idx % 40;
      float4 v;
      if (c4 < 20) {
        v = *reinterpret_cast<const float4*>(&bu[(kc + row) * PS + 4 * c4]);
      } else {
        v = *reinterpret_cast<const float4*>(&bz[(kc + row) * PS + 4 * (c4 - 20)]);
      }
      *reinterpret_cast<float4*>(&bt[row][4 * c4]) = v;
    }
    __syncthreads();

#pragma unroll
    for (int kk = 0; kk < 32; ++kk) {
      float4 xa = *reinterpret_cast<const float4*>(&xt[kk][ty * 4]);
#pragma unroll
      for (int j = 0; j < 5; ++j) {
        float4 bv = *reinterpret_cast<const float4*>(&bt[kk][tx * 20 + 4 * j]);
        acc[0][4*j+0] += xa.x * bv.x; acc[0][4*j+1] += xa.x * bv.y;
        acc[0][4*j+2] += xa.x * bv.z; acc[0][4*j+3] += xa.x * bv.w;
        acc[1][4*j+0] += xa.y * bv.x; acc[1][4*j+1] += xa.y * bv.y;
        acc[1][4*j+2] += xa.y * bv.z; acc[1][4*j+3] += xa.y * bv.w;
        acc[2][4*j+0] += xa.z * bv.x; acc[2][4*j+1] += xa.z * bv.y;
        acc[2][4*j+2] += xa.z * bv.z; acc[2][4*j+3] += xa.z * bv.w;
        acc[3][4*j+0] += xa.w * bv.x; acc[3][4*j+1] += xa.w * bv.y;
        acc[3][4*j+2] += xa.w * bv.z; acc[3][4*j+3] += xa.w * bv.w;
      }
    }
  }

  // epilogue: coalesced float4 stores
#pragma unroll
  for (int m = 0; m < 4; ++m) {
    size_t row = r0 + (size_t)(ty * 4 + m);
#pragma unroll
    for (int j = 0; j < 5; ++j) {
      float4 o = make_float4(acc[m][4*j+0], acc[m][4*j+1],
                             acc[m][4*j+2], acc[m][4*j+3]);
      *reinterpret_cast<float4*>(&ut[row * CC + tx * 20 + 4 * j]) = o;
    }
  }
}

// ---------------------------------------------------------------------------
// Kernel 3: per-bag online softmax + weighted pooling.
// One thread per (bag, col): 8 bags per 640-thread block.
// zb[bag][c] = sum_r softmax(u[r][c]) * tz[r][c]   (the 1/b factor cancels:
// t = tz/b, z = segsum(w*t) = zraw/b, mean/std scale by 1/b, and the final
// b*(z-mean)/std equals b*(zraw-meanraw)/stdraw.)
// ---------------------------------------------------------------------------
__global__ __launch_bounds__(640) void bag_pool_k(
    const float* __restrict__ ut, const int* __restrict__ segstart,
    float* __restrict__ zb) {
  int tid = threadIdx.x;
  int g = tid / PS;     // 0..7
  int c = tid % PS;     // 0..79
  int bag = blockIdx.x * 8 + g;
  int s = segstart[bag];
  int e = segstart[bag + 1];
  float m = -3.4e38f, se = 0.f, st = 0.f;
  for (int r = s; r < e; ++r) {
    const float* row = ut + (size_t)r * CC;
    float v = row[c];
    float t = row[PS + c];
    float nm = fmaxf(m, v);
    float sc = __expf(m - nm);   // first iter: exp(-huge) = 0
    float ee = __expf(v - nm);
    se = se * sc + ee;
    st = st * sc + ee * t;
    m = nm;
  }
  zb[bag * PS + c] = (e > s) ? (st / se) : 0.f;
}

// ---------------------------------------------------------------------------
// Kernel 4: per-column stats over bags + b-scale + output write.
// One block per column c (80 blocks x 256 threads).
// out[b][c] = bval[c] * (zb[b][c] - mean[c]) / std[c]   (ddof=1)
// ---------------------------------------------------------------------------
__device__ inline float wave_sum(float v) {
#pragma unroll
  for (int o = 32; o > 0; o >>= 1) v += __shfl_down(v, o, 64);
  return v;
}

__global__ __launch_bounds__(256) void finalize_k(
    const float* __restrict__ bz, const float* __restrict__ zb,
    float* __restrict__ out) {
  const int c = blockIdx.x;   // 0..79
  const int t = threadIdx.x;  // 0..255  (== Q rows for beta_z reduction)

  float bvz = bz[t * PS + c];
  float bsq = bvz * bvz;

  float s = 0.f, ss = 0.f;
  for (int b = t; b < BB; b += 256) {
    float z = zb[b * PS + c];
    s += z;
    ss += z * z;
  }

  __shared__ float w0[4], w1[4], w2[4];
  float a0 = wave_sum(bsq);
  float a1 = wave_sum(s);
  float a2 = wave_sum(ss);
  int wid = t >> 6, lane = t & 63;
  if (lane == 0) { w0[wid] = a0; w1[wid] = a1; w2[wid] = a2; }
  __syncthreads();

  __shared__ float sh[3];
  if (t == 0) {
    float B0 = w0[0] + w0[1] + w0[2] + w0[3];
    float S1 = w1[0] + w1[1] + w1[2] + w1[3];
    float S2 = w2[0] + w2[1] + w2[2] + w2[3];
    float bval = sqrtf(B0 / (float)QQ);
    float mean = S1 / (float)BB;
    float var = (S2 - (float)BB * mean * mean) / (float)(BB - 1);
    float sd = sqrtf(fmaxf(var, 0.f));
    if (!(sd > 0.f) || sd != sd) sd = 1.f;  // mirror ref's NaN->1 guard
    sh[0] = bval; sh[1] = mean; sh[2] = sd;
  }
  __syncthreads();
  float bval = sh[0], mean = sh[1], sd = sh[2];
  for (int b = t; b < BB; b += 256) {
    out[b * PS + c] = bval * (zb[b * PS + c] - mean) / sd;
  }
}

// ---------------------------------------------------------------------------
extern "C" void kernel_launch(void* const* d_in, const int* in_sizes, int n_in,
                              void* d_out, int out_size, void* d_ws, size_t ws_size,
                              hipStream_t stream) {
  const float* x   = (const float*)d_in[0];
  const float* bu  = (const float*)d_in[1];
  const float* bz  = (const float*)d_in[2];
  const int*   seg = (const int*)d_in[3];   // harness narrows int64 -> int32
  float* out = (float*)d_out;

  char* ws = (char*)d_ws;
  float* ut       = (float*)ws;                                       // N*160 f32
  float* zbuf     = (float*)(ws + (size_t)NN * CC * sizeof(float));   // B*80 f32
  int*   segstart = (int*)(ws + (size_t)NN * CC * sizeof(float)
                              + (size_t)BB * PS * sizeof(float));     // B+1 ints

  // Phase A: fused GEMM (independent of boundaries)
  gemm_k<<<NN / 128, 256, 0, stream>>>(x, bu, bz, ut);
  // Segment boundaries
  seg_bounds_k<<<(BB + 1 + 255) / 256, 256, 0, stream>>>(seg, segstart);
  // Phase B: per-bag online softmax + pooling
  bag_pool_k<<<BB / 8, 640, 0, stream>>>(ut, segstart, zbuf);
  // Phase C: stats + scale + write output
  finalize_k<<<PS, 256, 0, stream>>>(bz, zbuf, out);
}

// Round 3
// 207.114 us; speedup vs baseline: 2.0530x; 2.0530x over previous
//
#include <hip/hip_runtime.h>
#include <hip/hip_bf16.h>
#include <math.h>

#define NN 262144
#define QQ 256
#define CC 160   // combined cols: [0,80)=u (x@beta_u), [80,160)=tz (x@beta_z)
#define PS 80
#define BB 4096
#define BK 64

typedef short bf16x8 __attribute__((ext_vector_type(8)));
typedef float f32x4  __attribute__((ext_vector_type(4)));

// round-to-nearest-even f32 -> bf16 bits
__device__ inline unsigned int bfbits(float f) {
  unsigned int u = __float_as_uint(f);
  return (u + 0x7FFFu + ((u >> 16) & 1u)) >> 16;
}

// ---------------------------------------------------------------------------
// Kernel 0: split B = [beta_u | beta_z] (f32 [256][160]) into bf16 hi/lo,
// stored TRANSPOSED [160][256] for contiguous-k fragment staging.
// ---------------------------------------------------------------------------
__global__ void bsplit_k(const float* __restrict__ bu, const float* __restrict__ bz,
                         unsigned short* __restrict__ bTh, unsigned short* __restrict__ bTl) {
  int c = blockIdx.x;     // 0..159
  int k = threadIdx.x;    // 0..255
  float v = (c < PS) ? bu[k * PS + c] : bz[k * PS + (c - PS)];
  unsigned int h = bfbits(v);
  float r = v - __uint_as_float(h << 16);
  unsigned int l = bfbits(r);
  bTh[c * QQ + k] = (unsigned short)h;
  bTl[c * QQ + k] = (unsigned short)l;
}

// ---------------------------------------------------------------------------
// Kernel 1: segment boundaries (seg_ids sorted, delivered as int32).
// ---------------------------------------------------------------------------
__global__ void seg_bounds_k(const int* __restrict__ seg, int* __restrict__ segstart) {
  int b = blockIdx.x * blockDim.x + threadIdx.x;
  if (b > BB) return;
  if (b == BB) { segstart[BB] = NN; return; }
  int lo = 0, hi = NN;
  while (lo < hi) {
    int mid = (lo + hi) >> 1;
    if (seg[mid] < b) lo = mid + 1; else hi = mid;
  }
  segstart[b] = lo;
}

// ---------------------------------------------------------------------------
// Kernel 2: MFMA GEMM  ut[N][160] = x[N][256] @ B[256][160]
// 3-term bf16 split: x ~ xh+xl, B ~ bh+bl; C = xh*bh + xh*bl + xl*bh.
// Block: 128 rows x 160 cols, 256 threads = 4 waves in 2x2 grid
// (wave tile 64 rows x 80 cols = 4x5 frags of 16x16, K-chunks of 64).
// LDS XOR-swizzle (byte ^= (row&7)<<4) on write AND read -> conflict-free
// ds_read_b128 fragments. A converted in-register during staging; B read
// pre-split from bTh/bTl.
// MFMA layouts (gfx950 16x16x32 bf16):
//   A: row = lane&15, k = 8*(lane>>4)+j (j=0..7 contiguous)
//   B: col = lane&15, same k range
//   D: col = lane&15, row = (lane>>4)*4 + reg        [measured m89]
// ---------------------------------------------------------------------------
__global__ __launch_bounds__(256, 2) void gemm_mfma_k(
    const float* __restrict__ x,
    const unsigned short* __restrict__ bTh, const unsigned short* __restrict__ bTl,
    float* __restrict__ ut) {
  __shared__ __align__(16) unsigned short xh_s[128 * BK];  // 16 KB
  __shared__ __align__(16) unsigned short xl_s[128 * BK];  // 16 KB
  __shared__ __align__(16) unsigned short bh_s[CC * BK];   // 20 KB
  __shared__ __align__(16) unsigned short bl_s[CC * BK];   // 20 KB

  const int tid  = threadIdx.x;
  const int wid  = tid >> 6;
  const int lane = tid & 63;
  const size_t r0 = (size_t)blockIdx.x * 128;

  const int wr   = (wid >> 1) * 64;   // wave row offset
  const int wc   = (wid & 1) * 80;    // wave col offset
  const int lrow = lane & 15;         // frag row (A) / col (B)
  const int lk16 = lane >> 4;         // k-group: k = 8*lk16 + j

  f32x4 acc[4][5];
#pragma unroll
  for (int m = 0; m < 4; ++m)
#pragma unroll
    for (int n = 0; n < 5; ++n) acc[m][n] = (f32x4){0.f, 0.f, 0.f, 0.f};

  for (int kc = 0; kc < QQ; kc += BK) {
    __syncthreads();
    // ---- stage A: coalesced float4 loads, split to bf16 hi/lo, swizzled writes
#pragma unroll
    for (int i = 0; i < 8; ++i) {
      int idx = tid + 256 * i;        // 2048 float4 = 128 rows x 16
      int row = idx >> 4;
      int f4  = idx & 15;             // k = 4*f4
      float4 v = *reinterpret_cast<const float4*>(&x[(r0 + row) * QQ + kc + 4 * f4]);
      unsigned int h0 = bfbits(v.x), h1 = bfbits(v.y), h2 = bfbits(v.z), h3 = bfbits(v.w);
      float q0 = v.x - __uint_as_float(h0 << 16);
      float q1 = v.y - __uint_as_float(h1 << 16);
      float q2 = v.z - __uint_as_float(h2 << 16);
      float q3 = v.w - __uint_as_float(h3 << 16);
      unsigned int l0 = bfbits(q0), l1 = bfbits(q1), l2 = bfbits(q2), l3 = bfbits(q3);
      int byte = (8 * f4) ^ ((row & 7) << 4);   // 8B chunk stays in 16B slot
      uint2 hw = make_uint2(h0 | (h1 << 16), h2 | (h3 << 16));
      uint2 lw = make_uint2(l0 | (l1 << 16), l2 | (l3 << 16));
      *reinterpret_cast<uint2*>(reinterpret_cast<char*>(xh_s) + row * 128 + byte) = hw;
      *reinterpret_cast<uint2*>(reinterpret_cast<char*>(xl_s) + row * 128 + byte) = lw;
    }
    // ---- stage B: 16B coalesced loads of pre-split bf16, swizzled writes
#pragma unroll
    for (int i = 0; i < 5; ++i) {
      int idx = tid + 256 * i;        // 1280 chunks = 160 cols x 8
      int c = idx >> 3;
      int g = idx & 7;                // k = 8*g
      uint4 hv = *reinterpret_cast<const uint4*>(bTh + c * QQ + kc + 8 * g);
      uint4 lv = *reinterpret_cast<const uint4*>(bTl + c * QQ + kc + 8 * g);
      int byte = (16 * g) ^ ((c & 7) << 4);
      *reinterpret_cast<uint4*>(reinterpret_cast<char*>(bh_s) + c * 128 + byte) = hv;
      *reinterpret_cast<uint4*>(reinterpret_cast<char*>(bl_s) + c * 128 + byte) = lv;
    }
    __syncthreads();
    // ---- compute
#pragma unroll
    for (int ks = 0; ks < BK; ks += 32) {
      bf16x8 ah[4], al[4];
#pragma unroll
      for (int m = 0; m < 4; ++m) {
        int r = wr + m * 16 + lrow;
        int byte = ((ks + 8 * lk16) * 2) ^ ((r & 7) << 4);
        ah[m] = *reinterpret_cast<const bf16x8*>(reinterpret_cast<const char*>(xh_s) + r * 128 + byte);
        al[m] = *reinterpret_cast<const bf16x8*>(reinterpret_cast<const char*>(xl_s) + r * 128 + byte);
      }
#pragma unroll
      for (int n = 0; n < 5; ++n) {
        int c = wc + n * 16 + lrow;
        int byte = ((ks + 8 * lk16) * 2) ^ ((c & 7) << 4);
        bf16x8 bh = *reinterpret_cast<const bf16x8*>(reinterpret_cast<const char*>(bh_s) + c * 128 + byte);
        bf16x8 bl = *reinterpret_cast<const bf16x8*>(reinterpret_cast<const char*>(bl_s) + c * 128 + byte);
#pragma unroll
        for (int m = 0; m < 4; ++m) {
          acc[m][n] = __builtin_amdgcn_mfma_f32_16x16x32_bf16(ah[m], bh, acc[m][n], 0, 0, 0);
          acc[m][n] = __builtin_amdgcn_mfma_f32_16x16x32_bf16(al[m], bh, acc[m][n], 0, 0, 0);
          acc[m][n] = __builtin_amdgcn_mfma_f32_16x16x32_bf16(ah[m], bl, acc[m][n], 0, 0, 0);
        }
      }
    }
  }
  // ---- epilogue: D col=lane&15, row=(lane>>4)*4+reg
#pragma unroll
  for (int m = 0; m < 4; ++m) {
#pragma unroll
    for (int n = 0; n < 5; ++n) {
#pragma unroll
      for (int r = 0; r < 4; ++r) {
        size_t row = r0 + wr + m * 16 + lk16 * 4 + r;
        int col = wc + n * 16 + lrow;
        ut[row * CC + col] = acc[m][n][r];
      }
    }
  }
}

// ---------------------------------------------------------------------------
// Kernel 3: per-bag online softmax + weighted pooling (1/b cancels).
// ---------------------------------------------------------------------------
__global__ __launch_bounds__(640) void bag_pool_k(
    const float* __restrict__ ut, const int* __restrict__ segstart,
    float* __restrict__ zb) {
  int tid = threadIdx.x;
  int g = tid / PS;
  int c = tid % PS;
  int bag = blockIdx.x * 8 + g;
  int s = segstart[bag];
  int e = segstart[bag + 1];
  float m = -3.4e38f, se = 0.f, st = 0.f;
  for (int r = s; r < e; ++r) {
    const float* row = ut + (size_t)r * CC;
    float v = row[c];
    float t = row[PS + c];
    float nm = fmaxf(m, v);
    float sc = __expf(m - nm);
    float ee = __expf(v - nm);
    se = se * sc + ee;
    st = st * sc + ee * t;
    m = nm;
  }
  zb[bag * PS + c] = (e > s) ? (st / se) : 0.f;
}

// ---------------------------------------------------------------------------
// Kernel 4: per-column stats + b-scale, IN PLACE on d_out (zb == out).
// Safe: all stats reads happen before the barrier; element writes are by the
// same thread that read them.
// ---------------------------------------------------------------------------
__device__ inline float wave_sum(float v) {
#pragma unroll
  for (int o = 32; o > 0; o >>= 1) v += __shfl_down(v, o, 64);
  return v;
}

__global__ __launch_bounds__(256) void finalize_k(
    const float* __restrict__ bz, float* __restrict__ zb_out) {
  const int c = blockIdx.x;
  const int t = threadIdx.x;

  float bvz = bz[t * PS + c];
  float bsq = bvz * bvz;

  float s = 0.f, ss = 0.f;
  for (int b = t; b < BB; b += 256) {
    float z = zb_out[b * PS + c];
    s += z;
    ss += z * z;
  }

  __shared__ float w0[4], w1[4], w2[4];
  float a0 = wave_sum(bsq);
  float a1 = wave_sum(s);
  float a2 = wave_sum(ss);
  int wid = t >> 6, lane = t & 63;
  if (lane == 0) { w0[wid] = a0; w1[wid] = a1; w2[wid] = a2; }
  __syncthreads();

  __shared__ float sh[3];
  if (t == 0) {
    float B0 = w0[0] + w0[1] + w0[2] + w0[3];
    float S1 = w1[0] + w1[1] + w1[2] + w1[3];
    float S2 = w2[0] + w2[1] + w2[2] + w2[3];
    float bval = sqrtf(B0 / (float)QQ);
    float mean = S1 / (float)BB;
    float var = (S2 - (float)BB * mean * mean) / (float)(BB - 1);
    float sd = sqrtf(fmaxf(var, 0.f));
    if (!(sd > 0.f) || sd != sd) sd = 1.f;
    sh[0] = bval; sh[1] = mean; sh[2] = sd;
  }
  __syncthreads();
  float bval = sh[0], mean = sh[1], sd = sh[2];
  for (int b = t; b < BB; b += 256) {
    zb_out[b * PS + c] = bval * (zb_out[b * PS + c] - mean) / sd;
  }
}

// ---------------------------------------------------------------------------
extern "C" void kernel_launch(void* const* d_in, const int* in_sizes, int n_in,
                              void* d_out, int out_size, void* d_ws, size_t ws_size,
                              hipStream_t stream) {
  const float* x   = (const float*)d_in[0];
  const float* bu  = (const float*)d_in[1];
  const float* bz  = (const float*)d_in[2];
  const int*   seg = (const int*)d_in[3];   // harness narrows int64 -> int32
  float* out = (float*)d_out;

  char* ws = (char*)d_ws;
  float* ut = (float*)ws;                                  // N*160 f32 = 160 MB
  size_t off = (size_t)NN * CC * sizeof(float);            // 167772160
  int* segstart = (int*)(ws + off);                        // (B+1) ints
  off += 16400;                                            // padded, keeps 16B align
  unsigned short* bTh = (unsigned short*)(ws + off);       // 160*256 bf16
  off += (size_t)CC * QQ * sizeof(unsigned short);
  unsigned short* bTl = (unsigned short*)(ws + off);

  bsplit_k<<<CC, QQ, 0, stream>>>(bu, bz, bTh, bTl);
  seg_bounds_k<<<(BB + 1 + 255) / 256, 256, 0, stream>>>(seg, segstart);
  gemm_mfma_k<<<NN / 128, 256, 0, stream>>>(x, bTh, bTl, ut);
  bag_pool_k<<<BB / 8, 640, 0, stream>>>(ut, segstart, out);
  finalize_k<<<PS, 256, 0, stream>>>(bz, out);
}

// Round 4
// 155.816 us; speedup vs baseline: 2.7289x; 1.3292x over previous
//
#include <hip/hip_runtime.h>
#include <hip/hip_bf16.h>
#include <math.h>

#define NN 262144
#define QQ 256
#define CC 160   // combined cols: [0,80)=u (x@beta_u), [80,160)=tz (x@beta_z)
#define PS 80
#define BB 4096
#define BK 64
#define NSLOT 4  // partial slots per bag (bag spans <=2 row-strips; 4 = safety)

typedef short bf16x8 __attribute__((ext_vector_type(8)));
typedef float f32x4  __attribute__((ext_vector_type(4)));

// round-to-nearest-even f32 -> bf16 bits
__device__ inline unsigned int bfbits(float f) {
  unsigned int u = __float_as_uint(f);
  return (u + 0x7FFFu + ((u >> 16) & 1u)) >> 16;
}

// ---------------------------------------------------------------------------
// Kernel 0: split B = [beta_u | beta_z] (f32 [256][160]) into bf16 hi/lo,
// stored TRANSPOSED [160][256].
// ---------------------------------------------------------------------------
__global__ void bsplit_k(const float* __restrict__ bu, const float* __restrict__ bz,
                         unsigned short* __restrict__ bTh, unsigned short* __restrict__ bTl) {
  int c = blockIdx.x;     // 0..159
  int k = threadIdx.x;    // 0..255
  float v = (c < PS) ? bu[k * PS + c] : bz[k * PS + (c - PS)];
  unsigned int h = bfbits(v);
  float r = v - __uint_as_float(h << 16);
  unsigned int l = bfbits(r);
  bTh[c * QQ + k] = (unsigned short)h;
  bTl[c * QQ + k] = (unsigned short)l;
}

// ---------------------------------------------------------------------------
// Kernel 1: segment boundaries (seg_ids sorted, delivered as int32).
// ---------------------------------------------------------------------------
__global__ void seg_bounds_k(const int* __restrict__ seg, int* __restrict__ segstart) {
  int b = blockIdx.x * blockDim.x + threadIdx.x;
  if (b > BB) return;
  if (b == BB) { segstart[BB] = NN; return; }
  int lo = 0, hi = NN;
  while (lo < hi) {
    int mid = (lo + hi) >> 1;
    if (seg[mid] < b) lo = mid + 1; else hi = mid;
  }
  segstart[b] = lo;
}

// ---------------------------------------------------------------------------
// Kernel 2: init softmax partials (m = sentinel, se = st = 0).
// ---------------------------------------------------------------------------
__global__ __launch_bounds__(256) void init_partials_k(
    float* __restrict__ pm, float* __restrict__ pse, float* __restrict__ pst) {
  int i = blockIdx.x * 256 + threadIdx.x;   // total BB*NSLOT*PS = 1310720
  if (i < BB * NSLOT * PS) { pm[i] = -3.4e38f; pse[i] = 0.f; pst[i] = 0.f; }
}

// ---------------------------------------------------------------------------
// Kernel 3: FUSED  [GEMM 128x160x256 per block] + [in-LDS segmented online
// softmax-pool partials].
// 512 threads = 8 waves (4 row-waves x 2 col-waves; wave tile 32 rows x 80
// cols = 2x5 frags). 3-term bf16 split MFMA identical to verified r3 kernel.
// LDS union: staging (xh 16K | xl 16K | bh 20K | bl 20K = 72K) reused after
// K-loop as result (res_u f32 [128][80] = 40K | res_t bf16 [128][80] = 20K).
// ---------------------------------------------------------------------------
__global__ __launch_bounds__(512, 4) void fused_k(
    const float* __restrict__ x,
    const unsigned short* __restrict__ bTh, const unsigned short* __restrict__ bTl,
    const int* __restrict__ seg, const int* __restrict__ segstart,
    float* __restrict__ pm, float* __restrict__ pse, float* __restrict__ pst) {
  __shared__ __align__(16) char smem[73728];
  char* xh_c = smem;                  // 16384
  char* xl_c = smem + 16384;          // 16384
  char* bh_c = smem + 32768;          // 20480
  char* bl_c = smem + 53248;          // 20480 (end 73728)
  float* res_u          = (float*)smem;            // 40960
  unsigned short* res_t = (unsigned short*)(smem + 40960);  // 20480 (end 61440)

  const int tid  = threadIdx.x;
  const int wid  = tid >> 6;
  const int lane = tid & 63;
  const int rs   = blockIdx.x * 128;

  const int wr   = (wid & 3) * 32;    // wave row offset (0,32,64,96)
  const int cw   = wid >> 2;          // col-wave: 0 -> u cols, 1 -> tz cols
  const int wc   = cw * 80;
  const int lrow = lane & 15;
  const int lk16 = lane >> 4;

  f32x4 acc[2][5];
#pragma unroll
  for (int m = 0; m < 2; ++m)
#pragma unroll
    for (int n = 0; n < 5; ++n) acc[m][n] = (f32x4){0.f, 0.f, 0.f, 0.f};

  for (int kc = 0; kc < QQ; kc += BK) {
    __syncthreads();
    // ---- stage A: coalesced float4, split f32 -> bf16 hi/lo, swizzled write
#pragma unroll
    for (int i = 0; i < 4; ++i) {
      int idx = tid + 512 * i;        // 2048 float4 = 128 rows x 16
      int row = idx >> 4;
      int f4  = idx & 15;
      float4 v = *reinterpret_cast<const float4*>(
          &x[(size_t)(rs + row) * QQ + kc + 4 * f4]);
      unsigned int h0 = bfbits(v.x), h1 = bfbits(v.y), h2 = bfbits(v.z), h3 = bfbits(v.w);
      float q0 = v.x - __uint_as_float(h0 << 16);
      float q1 = v.y - __uint_as_float(h1 << 16);
      float q2 = v.z - __uint_as_float(h2 << 16);
      float q3 = v.w - __uint_as_float(h3 << 16);
      unsigned int l0 = bfbits(q0), l1 = bfbits(q1), l2 = bfbits(q2), l3 = bfbits(q3);
      int byte = (8 * f4) ^ ((row & 7) << 4);
      uint2 hw = make_uint2(h0 | (h1 << 16), h2 | (h3 << 16));
      uint2 lw = make_uint2(l0 | (l1 << 16), l2 | (l3 << 16));
      *reinterpret_cast<uint2*>(xh_c + row * 128 + byte) = hw;
      *reinterpret_cast<uint2*>(xl_c + row * 128 + byte) = lw;
    }
    // ---- stage B: 16B coalesced pre-split bf16, swizzled write
#pragma unroll
    for (int i = 0; i < 3; ++i) {
      int idx = tid + 512 * i;        // 1280 chunks = 160 cols x 8
      if (idx < 1280) {
        int c = idx >> 3;
        int g = idx & 7;
        uint4 hv = *reinterpret_cast<const uint4*>(bTh + c * QQ + kc + 8 * g);
        uint4 lv = *reinterpret_cast<const uint4*>(bTl + c * QQ + kc + 8 * g);
        int byte = (16 * g) ^ ((c & 7) << 4);
        *reinterpret_cast<uint4*>(bh_c + c * 128 + byte) = hv;
        *reinterpret_cast<uint4*>(bl_c + c * 128 + byte) = lv;
      }
    }
    __syncthreads();
    // ---- compute
#pragma unroll
    for (int ks = 0; ks < BK; ks += 32) {
      bf16x8 ah[2], al[2];
#pragma unroll
      for (int m = 0; m < 2; ++m) {
        int r = wr + m * 16 + lrow;
        int byte = ((ks + 8 * lk16) * 2) ^ ((r & 7) << 4);
        ah[m] = *reinterpret_cast<const bf16x8*>(xh_c + r * 128 + byte);
        al[m] = *reinterpret_cast<const bf16x8*>(xl_c + r * 128 + byte);
      }
#pragma unroll
      for (int n = 0; n < 5; ++n) {
        int c = wc + n * 16 + lrow;
        int byte = ((ks + 8 * lk16) * 2) ^ ((c & 7) << 4);
        bf16x8 bh = *reinterpret_cast<const bf16x8*>(bh_c + c * 128 + byte);
        bf16x8 bl = *reinterpret_cast<const bf16x8*>(bl_c + c * 128 + byte);
#pragma unroll
        for (int m = 0; m < 2; ++m) {
          acc[m][n] = __builtin_amdgcn_mfma_f32_16x16x32_bf16(ah[m], bh, acc[m][n], 0, 0, 0);
          acc[m][n] = __builtin_amdgcn_mfma_f32_16x16x32_bf16(al[m], bh, acc[m][n], 0, 0, 0);
          acc[m][n] = __builtin_amdgcn_mfma_f32_16x16x32_bf16(ah[m], bl, acc[m][n], 0, 0, 0);
        }
      }
    }
  }

  // ---- epilogue: acc -> LDS result (overlaps staging region; barrier first)
  __syncthreads();
#pragma unroll
  for (int m = 0; m < 2; ++m) {
#pragma unroll
    for (int n = 0; n < 5; ++n) {
#pragma unroll
      for (int r = 0; r < 4; ++r) {
        int row = wr + m * 16 + lk16 * 4 + r;
        int col = n * 16 + lrow;                 // 0..79 within half
        if (cw == 0) res_u[row * 80 + col] = acc[m][n][r];
        else         res_t[row * 80 + col] = (unsigned short)bfbits(acc[m][n][r]);
      }
    }
  }
  __syncthreads();

  // ---- segmented online softmax-pool over this 128-row strip
  int b0 = seg[rs];
  int b1 = seg[rs + 127];
  int nu = (b1 - b0 + 1) * PS;
  for (int u = tid; u < nu; u += 512) {
    int bag = b0 + u / PS;
    int c   = u % PS;
    int sb  = segstart[bag];
    int lo  = max(sb, rs) - rs;
    int hi  = min(segstart[bag + 1], rs + 128) - rs;
    float m_ = -3.4e38f, se = 0.f, st = 0.f;
    for (int r = lo; r < hi; ++r) {
      float v = res_u[r * 80 + c];
      float t = __uint_as_float((unsigned int)res_t[r * 80 + c] << 16);
      float nm = fmaxf(m_, v);
      float sc = __expf(m_ - nm);
      float ee = __expf(v - nm);
      se = se * sc + ee;
      st = st * sc + ee * t;
      m_ = nm;
    }
    int slot = blockIdx.x - (sb >> 7);   // which strip of this bag we are
    size_t p = ((size_t)bag * NSLOT + slot) * PS + c;
    pm[p] = m_; pse[p] = se; pst[p] = st;
  }
}

// ---------------------------------------------------------------------------
// Kernel 4: merge partial slots per (bag,col) -> zb (= d_out).
// ---------------------------------------------------------------------------
__global__ __launch_bounds__(256) void combine_k(
    const float* __restrict__ pm, const float* __restrict__ pse,
    const float* __restrict__ pst, float* __restrict__ zb) {
  int i = blockIdx.x * 256 + threadIdx.x;   // BB*PS = 327680
  if (i >= BB * PS) return;
  int bag = i / PS, c = i % PS;
  float m = -3.4e38f, se = 0.f, st = 0.f;
#pragma unroll
  for (int s = 0; s < NSLOT; ++s) {
    size_t p = ((size_t)bag * NSLOT + s) * PS + c;
    float m2 = pm[p], se2 = pse[p], st2 = pst[p];
    float nm = fmaxf(m, m2);
    float s1 = __expf(m - nm);    // sentinel-sentinel: exp(0)=1, se=0 -> ok
    float s2 = __expf(m2 - nm);
    se = se * s1 + se2 * s2;
    st = st * s1 + st2 * s2;
    m = nm;
  }
  zb[i] = (se > 0.f) ? st / se : 0.f;
}

// ---------------------------------------------------------------------------
// Kernel 5: per-column stats + b-scale, IN PLACE on d_out.
// ---------------------------------------------------------------------------
__device__ inline float wave_sum(float v) {
#pragma unroll
  for (int o = 32; o > 0; o >>= 1) v += __shfl_down(v, o, 64);
  return v;
}

__global__ __launch_bounds__(256) void finalize_k(
    const float* __restrict__ bz, float* __restrict__ zb_out) {
  const int c = blockIdx.x;
  const int t = threadIdx.x;

  float bvz = bz[t * PS + c];
  float bsq = bvz * bvz;

  float s = 0.f, ss = 0.f;
  for (int b = t; b < BB; b += 256) {
    float z = zb_out[b * PS + c];
    s += z;
    ss += z * z;
  }

  __shared__ float w0[4], w1[4], w2[4];
  float a0 = wave_sum(bsq);
  float a1 = wave_sum(s);
  float a2 = wave_sum(ss);
  int wid = t >> 6, lane = t & 63;
  if (lane == 0) { w0[wid] = a0; w1[wid] = a1; w2[wid] = a2; }
  __syncthreads();

  __shared__ float sh[3];
  if (t == 0) {
    float B0 = w0[0] + w0[1] + w0[2] + w0[3];
    float S1 = w1[0] + w1[1] + w1[2] + w1[3];
    float S2 = w2[0] + w2[1] + w2[2] + w2[3];
    float bval = sqrtf(B0 / (float)QQ);
    float mean = S1 / (float)BB;
    float var = (S2 - (float)BB * mean * mean) / (float)(BB - 1);
    float sd = sqrtf(fmaxf(var, 0.f));
    if (!(sd > 0.f) || sd != sd) sd = 1.f;
    sh[0] = bval; sh[1] = mean; sh[2] = sd;
  }
  __syncthreads();
  float bval = sh[0], mean = sh[1], sd = sh[2];
  for (int b = t; b < BB; b += 256) {
    zb_out[b * PS + c] = bval * (zb_out[b * PS + c] - mean) / sd;
  }
}

// ---------------------------------------------------------------------------
extern "C" void kernel_launch(void* const* d_in, const int* in_sizes, int n_in,
                              void* d_out, int out_size, void* d_ws, size_t ws_size,
                              hipStream_t stream) {
  const float* x   = (const float*)d_in[0];
  const float* bu  = (const float*)d_in[1];
  const float* bz  = (const float*)d_in[2];
  const int*   seg = (const int*)d_in[3];   // harness narrows int64 -> int32
  float* out = (float*)d_out;

  char* ws = (char*)d_ws;
  size_t off = 0;
  int* segstart = (int*)(ws + off);           off += 16640;         // 4097 ints, padded
  unsigned short* bTh = (unsigned short*)(ws + off); off += (size_t)CC * QQ * 2;
  unsigned short* bTl = (unsigned short*)(ws + off); off += (size_t)CC * QQ * 2;
  size_t pn = (size_t)BB * NSLOT * PS;
  float* pm  = (float*)(ws + off); off += pn * 4;
  float* pse = (float*)(ws + off); off += pn * 4;
  float* pst = (float*)(ws + off); off += pn * 4;

  bsplit_k<<<CC, QQ, 0, stream>>>(bu, bz, bTh, bTl);
  seg_bounds_k<<<(BB + 1 + 255) / 256, 256, 0, stream>>>(seg, segstart);
  init_partials_k<<<(int)((pn + 255) / 256), 256, 0, stream>>>(pm, pse, pst);
  fused_k<<<NN / 128, 512, 0, stream>>>(x, bTh, bTl, seg, segstart, pm, pse, pst);
  combine_k<<<(BB * PS + 255) / 256, 256, 0, stream>>>(pm, pse, pst, out);
  finalize_k<<<PS, 256, 0, stream>>>(bz, out);
}